// Round 5
// baseline (281.348 us; speedup 1.0000x reference)
//
#include <hip/hip_runtime.h>
#include <cmath>

typedef short bf16x8 __attribute__((ext_vector_type(8)));
typedef float f32x4 __attribute__((ext_vector_type(4)));

struct Coeffs { float k[11]; };

#define SPITCH 56   // ushort pitch: 112 B

__device__ __forceinline__ ushort f2bf(float f) {          // RNE bf16 (finite inputs)
    unsigned u = __float_as_uint(f);
    u += 0x7fff + ((u >> 16) & 1);
    return (ushort)(u >> 16);
}

__device__ __forceinline__ unsigned pk2(float lo, float hi) {  // packed bf16 pair
    unsigned d;
    asm("v_cvt_pk_bf16_f32 %0, %1, %2" : "=v"(d) : "v"(lo), "v"(hi));
    return d;
}

__device__ __forceinline__ float4 ld4s(const float* __restrict__ p, int r, int c, int H, int W) {
    float4 v = make_float4(0.f, 0.f, 0.f, 0.f);
    if (r >= 0 && r < H) {
        const float* row = p + (size_t)r * W;
        if (c >= 0 && c + 3 < W) {
            v = *reinterpret_cast<const float4*>(row + c);
        } else {
            if (c + 0 >= 0 && c + 0 < W) v.x = row[c + 0];
            if (c + 1 >= 0 && c + 1 < W) v.y = row[c + 1];
            if (c + 2 >= 0 && c + 2 < W) v.z = row[c + 2];
            if (c + 3 >= 0 && c + 3 < W) v.w = row[c + 3];
        }
    }
    return v;
}

union FragU { ushort us[8]; bf16x8 v; };
union RdU   { uint4 q; bf16x8 v; };

// =================== MFMA kernel: levels 0-1 only (large variance, bf16-safe) ======
__global__ __launch_bounds__(256)
void ssim_level_mfma(const float* __restrict__ i1, const float* __restrict__ i2,
                     float* __restrict__ o1, float* __restrict__ o2,
                     int H, int W, int tilesX,
                     double* __restrict__ accum, Coeffs cf)
{
    __shared__ __align__(16) ushort A_lds[5][48][SPITCH];   // 26.9 KB
    __shared__ __align__(16) ushort H_T [5][32][SPITCH];    // 17.9 KB
    __shared__ double red[2][4];

    const int tid  = threadIdx.x;
    const int lane = tid & 63;
    const int wave = tid >> 6;
    const int lj   = lane & 15;
    const int part = lane >> 4;

    const int bc    = blockIdx.y;
    const int tileY = blockIdx.x / tilesX;
    const int tileX = blockIdx.x - tileY * tilesX;
    const int r0 = tileY * 32;
    const int c0 = tileX * 32;
    const float* p1 = i1 + (size_t)bc * H * W;
    const float* p2 = i2 + (size_t)bc * H * W;

    // constant banded fragments
    float cfk[11];
    #pragma unroll
    for (int tt = 0; tt < 11; ++tt) cfk[tt] = cf.k[tt];
    FragU bHf, aVf;
    #pragma unroll
    for (int i = 0; i < 8; ++i) {
        const int kk = part * 8 + i;
        const int tH = kk - lj - 3;     // B_H[kk][j] = k[kk-j-3]
        const int tV = kk - lj;         // A_V[j][kk] = k[kk-j]
        float vH = 0.f, vV = 0.f;
        #pragma unroll
        for (int tt = 0; tt < 11; ++tt) {
            vH = (tH == tt) ? cfk[tt] : vH;
            vV = (tV == tt) ? cfk[tt] : vV;
        }
        bHf.us[i] = f2bf(vH);
        aVf.us[i] = f2bf(vV);
    }
    const bf16x8 bH = bHf.v;
    const bf16x8 aV = aVf.v;

    // ---- Phase 1: load + products + bf16 pack -> A_lds (192 thr); pool (64 thr) ----
    if (tid < 192) {
        const int row_rel = tid >> 2;          // 0..47
        const int colg    = tid & 3;
        const int gr  = r0 - 5 + row_rel;
        const int gc0 = c0 - 8 + 12 * colg;

        float a[12], b[12];
        if (gr >= 0 && gr < H && gc0 >= 0 && gc0 + 12 <= W) {
            const float* pa = p1 + (size_t)gr * W + gc0;
            const float* pb = p2 + (size_t)gr * W + gc0;
            #pragma unroll
            for (int g = 0; g < 3; ++g) {
                float4 va = *reinterpret_cast<const float4*>(pa + 4 * g);
                float4 vb = *reinterpret_cast<const float4*>(pb + 4 * g);
                a[4*g+0]=va.x; a[4*g+1]=va.y; a[4*g+2]=va.z; a[4*g+3]=va.w;
                b[4*g+0]=vb.x; b[4*g+1]=vb.y; b[4*g+2]=vb.z; b[4*g+3]=vb.w;
            }
        } else {
            #pragma unroll
            for (int g = 0; g < 3; ++g) {
                float4 va = ld4s(p1, gr, gc0 + 4 * g, H, W);
                float4 vb = ld4s(p2, gr, gc0 + 4 * g, H, W);
                a[4*g+0]=va.x; a[4*g+1]=va.y; a[4*g+2]=va.z; a[4*g+3]=va.w;
                b[4*g+0]=vb.x; b[4*g+1]=vb.y; b[4*g+2]=vb.z; b[4*g+3]=vb.w;
            }
        }

        unsigned pks[5][6];
        #pragma unroll
        for (int e = 0; e < 6; ++e) {
            const float a0 = a[2*e], a1 = a[2*e+1];
            const float b0 = b[2*e], b1 = b[2*e+1];
            pks[0][e] = pk2(a0, a1);
            pks[1][e] = pk2(b0, b1);
            pks[2][e] = pk2(a0*a0, a1*a1);
            pks[3][e] = pk2(b0*b0, b1*b1);
            pks[4][e] = pk2(a0*b0, a1*b1);
        }
        #pragma unroll
        for (int s = 0; s < 5; ++s) {
            ushort* dst = &A_lds[s][row_rel][12 * colg];
            *reinterpret_cast<uint2*>(dst + 0) = make_uint2(pks[s][0], pks[s][1]);
            *reinterpret_cast<uint2*>(dst + 4) = make_uint2(pks[s][2], pks[s][3]);
            *reinterpret_cast<uint2*>(dst + 8) = make_uint2(pks[s][4], pks[s][5]);
        }
    } else if (o1 != nullptr) {
        const int p = tid - 192;
        const int i = p & 15;
        const int h = p >> 4;
        const int gr0 = r0 + 2 * i;
        const int gc  = c0 + 8 * h;
        const float* pa = p1 + (size_t)gr0 * W + gc;
        const float* pb = p2 + (size_t)gr0 * W + gc;
        float4 a00 = *reinterpret_cast<const float4*>(pa);
        float4 a01 = *reinterpret_cast<const float4*>(pa + 4);
        float4 a10 = *reinterpret_cast<const float4*>(pa + W);
        float4 a11 = *reinterpret_cast<const float4*>(pa + W + 4);
        float4 b00 = *reinterpret_cast<const float4*>(pb);
        float4 b01 = *reinterpret_cast<const float4*>(pb + 4);
        float4 b10 = *reinterpret_cast<const float4*>(pb + W);
        float4 b11 = *reinterpret_cast<const float4*>(pb + W + 4);
        float4 oa, ob;
        oa.x = 0.25f*(a00.x+a00.y+a10.x+a10.y); oa.y = 0.25f*(a00.z+a00.w+a10.z+a10.w);
        oa.z = 0.25f*(a01.x+a01.y+a11.x+a11.y); oa.w = 0.25f*(a01.z+a01.w+a11.z+a11.w);
        ob.x = 0.25f*(b00.x+b00.y+b10.x+b10.y); ob.y = 0.25f*(b00.z+b00.w+b10.z+b10.w);
        ob.z = 0.25f*(b01.x+b01.y+b11.x+b11.y); ob.w = 0.25f*(b01.z+b01.w+b11.z+b11.w);
        const int W2 = W >> 1;
        const size_t base = (size_t)bc * (size_t)(H >> 1) * W2
                          + (size_t)(r0/2 + i) * W2 + (c0/2 + 4*h);
        *reinterpret_cast<float4*>(o1 + base) = oa;
        *reinterpret_cast<float4*>(o2 + base) = ob;
    }
    __syncthreads();

    // ---- Phase 2: H-conv via MFMA, write transposed bf16 ----
    const f32x4 zf = {0.f, 0.f, 0.f, 0.f};
    #pragma unroll
    for (int j = 0; j < 8; ++j) {
        const int id = wave + 4 * j;     // 30 MFMAs: rg(3) x cg(2) x s(5)
        if (id < 30) {
            const int rg  = id / 10;
            const int rem = id - rg * 10;
            const int cg  = rem / 5;
            const int s   = rem - cg * 5;
            RdU ar;
            ar.q = *reinterpret_cast<const uint4*>(&A_lds[s][rg*16 + lj][16*cg + part*8]);
            f32x4 d = __builtin_amdgcn_mfma_f32_16x16x32_bf16(ar.v, bH, zf, 0, 0, 0);
            uint2 w2 = make_uint2(pk2(d[0], d[1]), pk2(d[2], d[3]));
            *reinterpret_cast<uint2*>(&H_T[s][16*cg + lj][rg*16 + part*4]) = w2;
        }
    }
    __syncthreads();

    // ---- Phase 3: V-conv via MFMA + SSIM ----
    const int rg2 = wave >> 1;
    const int cg2 = wave & 1;
    f32x4 acc[5];
    #pragma unroll
    for (int s = 0; s < 5; ++s) {
        RdU br;
        br.q = *reinterpret_cast<const uint4*>(&H_T[s][16*cg2 + lj][rg2*16 + part*8]);
        acc[s] = __builtin_amdgcn_mfma_f32_16x16x32_bf16(aV, br.v, zf, 0, 0, 0);
    }

    const float C1 = 1e-4f, C2 = 9e-4f;
    float ssim_acc = 0.f, cs_acc = 0.f;
    #pragma unroll
    for (int r = 0; r < 4; ++r) {
        const float mu1 = acc[0][r], mu2 = acc[1][r];
        const float m11 = acc[2][r], m22 = acc[3][r], m12 = acc[4][r];
        const float mu1s = mu1 * mu1, mu2s = mu2 * mu2, mu12 = mu1 * mu2;
        const float v1 = 2.f * (m12 - mu12) + C2;
        const float v2 = (m11 - mu1s) + (m22 - mu2s) + C2;
        cs_acc   += v1 / v2;
        ssim_acc += ((2.f * mu12 + C1) * v1) / ((mu1s + mu2s + C1) * v2);
    }

    double sd = (double)ssim_acc, cd = (double)cs_acc;
    #pragma unroll
    for (int off = 32; off > 0; off >>= 1) {
        sd += __shfl_down(sd, off);
        cd += __shfl_down(cd, off);
    }
    if ((tid & 63) == 0) { red[0][wave] = sd; red[1][wave] = cd; }
    __syncthreads();
    if (tid == 0) {
        double s = red[0][0] + red[0][1] + red[0][2] + red[0][3];
        double c = red[1][0] + red[1][1] + red[1][2] + red[1][3];
        int slot = (blockIdx.x + blockIdx.y) & 63;
        atomicAdd(&accum[slot], s);
        atomicAdd(&accum[64 + slot], c);
    }
}

// =================== f32 kernel (R3, proven): levels 2-4 ===========================
#define TWF 32
#define THF 32
#define SPF 33
#define HRF 42

__global__ __launch_bounds__(256)
void ssim_level_f32(const float* __restrict__ i1, const float* __restrict__ i2,
                    float* __restrict__ o1, float* __restrict__ o2,
                    int H, int W, int tilesX,
                    double* __restrict__ accum, Coeffs cf)
{
    __shared__ __align__(16) float varr[5][HRF][SPF];
    __shared__ __align__(16) float phl[2][16][16];
    __shared__ double red[2][4];

    const int tid = threadIdx.x;
    const int bc  = blockIdx.y;
    const int tileY = blockIdx.x / tilesX;
    const int tileX = blockIdx.x - tileY * tilesX;
    const int r0 = tileY * THF;
    const int c0 = tileX * TWF;
    const float* p1 = i1 + (size_t)bc * H * W;
    const float* p2 = i2 + (size_t)bc * H * W;

    const int row_rel = tid >> 2;
    const int j  = tid & 3;
    const int cl = 8 * j;
    float hpA[4], hpB[4];
    bool pool_thread = false;

    if (tid < HRF * 4) {
        const int gr  = r0 + row_rel - 5;
        const int gcb = c0 + cl - 8;

        float a[24], b[24];
        if (gr >= 0 && gr < H && gcb >= 0 && gcb + 24 <= W) {
            const float* pa = p1 + (size_t)gr * W + gcb;
            const float* pb = p2 + (size_t)gr * W + gcb;
            #pragma unroll
            for (int g = 0; g < 6; ++g) {
                float4 va = *reinterpret_cast<const float4*>(pa + 4 * g);
                float4 vb = *reinterpret_cast<const float4*>(pb + 4 * g);
                a[4*g+0]=va.x; a[4*g+1]=va.y; a[4*g+2]=va.z; a[4*g+3]=va.w;
                b[4*g+0]=vb.x; b[4*g+1]=vb.y; b[4*g+2]=vb.z; b[4*g+3]=vb.w;
            }
        } else {
            #pragma unroll
            for (int g = 0; g < 6; ++g) {
                float4 va = ld4s(p1, gr, gcb + 4 * g, H, W);
                float4 vb = ld4s(p2, gr, gcb + 4 * g, H, W);
                a[4*g+0]=va.x; a[4*g+1]=va.y; a[4*g+2]=va.z; a[4*g+3]=va.w;
                b[4*g+0]=vb.x; b[4*g+1]=vb.y; b[4*g+2]=vb.z; b[4*g+3]=vb.w;
            }
        }

        float acc[5][8] = {};
        #pragma unroll
        for (int i = 0; i < 24; ++i) {
            float av = a[i], bv = b[i];
            float pa2 = av * av, pb2 = bv * bv, pab = av * bv;
            #pragma unroll
            for (int jo = 0; jo < 8; ++jo) {
                const int t = i - 3 - jo;
                if (t >= 0 && t <= 10) {
                    const float kk = cf.k[t];
                    acc[0][jo] += kk * av;  acc[1][jo] += kk * bv;
                    acc[2][jo] += kk * pa2; acc[3][jo] += kk * pb2;
                    acc[4][jo] += kk * pab;
                }
            }
        }
        #pragma unroll
        for (int s = 0; s < 5; ++s) {
            *reinterpret_cast<float4*>(&varr[s][row_rel][cl]) =
                make_float4(acc[s][0], acc[s][1], acc[s][2], acc[s][3]);
            *reinterpret_cast<float4*>(&varr[s][row_rel][cl + 4]) =
                make_float4(acc[s][4], acc[s][5], acc[s][6], acc[s][7]);
        }

        if (o1 != nullptr && row_rel >= 5 && row_rel <= 36) {
            #pragma unroll
            for (int p = 0; p < 4; ++p) {
                hpA[p] = a[8 + 2*p] + a[9 + 2*p];
                hpB[p] = b[8 + 2*p] + b[9 + 2*p];
            }
            if (row_rel & 1) {
                const int i = (row_rel - 5) >> 1;
                *reinterpret_cast<float4*>(&phl[0][i][4*j]) = make_float4(hpA[0],hpA[1],hpA[2],hpA[3]);
                *reinterpret_cast<float4*>(&phl[1][i][4*j]) = make_float4(hpB[0],hpB[1],hpB[2],hpB[3]);
            } else if (row_rel >= 6) {
                pool_thread = true;
            }
        }
    }
    __syncthreads();

    if (pool_thread) {
        const int i = (row_rel - 6) >> 1;
        const int W2 = W >> 1;
        float4 qa = *reinterpret_cast<const float4*>(&phl[0][i][4*j]);
        float4 qb = *reinterpret_cast<const float4*>(&phl[1][i][4*j]);
        qa.x = 0.25f*(qa.x + hpA[0]); qa.y = 0.25f*(qa.y + hpA[1]);
        qa.z = 0.25f*(qa.z + hpA[2]); qa.w = 0.25f*(qa.w + hpA[3]);
        qb.x = 0.25f*(qb.x + hpB[0]); qb.y = 0.25f*(qb.y + hpB[1]);
        qb.z = 0.25f*(qb.z + hpB[2]); qb.w = 0.25f*(qb.w + hpB[3]);
        const size_t base = (size_t)bc * (size_t)(H >> 1) * W2
                          + (size_t)(r0/2 + i) * W2 + (c0/2 + 4*j);
        *reinterpret_cast<float4*>(o1 + base) = qa;
        *reinterpret_cast<float4*>(o2 + base) = qb;
    }

    const int col = tid & 31;
    const int rg  = tid >> 5;

    float acc[5][4] = {};
    #pragma unroll
    for (int t = 0; t < 14; ++t) {
        const int m = rg * 4 + t;
        #pragma unroll
        for (int s = 0; s < 5; ++s) {
            const float val = varr[s][m][col];
            #pragma unroll
            for (int i = 0; i < 4; ++i) {
                const int tap = t - i;
                if (tap >= 0 && tap <= 10) acc[s][i] += cf.k[tap] * val;
            }
        }
    }

    const float C1 = 1e-4f, C2 = 9e-4f;
    float ssim_acc = 0.f, cs_acc = 0.f;
    #pragma unroll
    for (int i = 0; i < 4; ++i) {
        const float mu1 = acc[0][i], mu2 = acc[1][i];
        const float m11 = acc[2][i], m22 = acc[3][i], m12 = acc[4][i];
        const float mu1s = mu1 * mu1, mu2s = mu2 * mu2, mu12 = mu1 * mu2;
        const float v1 = 2.f * (m12 - mu12) + C2;
        const float v2 = (m11 - mu1s) + (m22 - mu2s) + C2;
        cs_acc   += v1 / v2;
        ssim_acc += ((2.f * mu12 + C1) * v1) / ((mu1s + mu2s + C1) * v2);
    }

    double sd = (double)ssim_acc, cd = (double)cs_acc;
    #pragma unroll
    for (int off = 32; off > 0; off >>= 1) {
        sd += __shfl_down(sd, off);
        cd += __shfl_down(cd, off);
    }
    const int wave = tid >> 6, lane = tid & 63;
    if (lane == 0) { red[0][wave] = sd; red[1][wave] = cd; }
    __syncthreads();
    if (tid == 0) {
        double s = red[0][0] + red[0][1] + red[0][2] + red[0][3];
        double c = red[1][0] + red[1][1] + red[1][2] + red[1][3];
        int slot = (blockIdx.x + blockIdx.y) & 63;
        atomicAdd(&accum[slot], s);
        atomicAdd(&accum[64 + slot], c);
    }
}

__global__ __launch_bounds__(64)
void finalize_kernel(const double* __restrict__ accum,  // [5][2][64]
                     float* __restrict__ out, int BC)
{
    __shared__ double sums[5][2];
    int tid = threadIdx.x;
    for (int lvl = 0; lvl < 5; ++lvl) {
        for (int m = 0; m < 2; ++m) {
            double v = accum[(lvl * 2 + m) * 64 + tid];
            for (int off = 32; off > 0; off >>= 1) v += __shfl_down(v, off);
            if (tid == 0) sums[lvl][m] = v;
        }
    }
    __syncthreads();
    if (tid == 0) {
        const double w[5] = {0.0448, 0.2856, 0.3001, 0.2363, 0.1333};
        double prod = 1.0;
        for (int lvl = 0; lvl < 5; ++lvl) {
            int hw = (512 >> lvl);
            double cnt = (double)BC * (double)hw * (double)hw;
            double mssim = sums[lvl][0] / cnt;
            double mcs   = sums[lvl][1] / cnt;
            if (lvl < 4) {
                prod *= pow(mcs, w[lvl]);
            } else {
                double p2 = pow(mssim, w[4]);
                prod *= p2 * p2 * p2 * p2;
            }
        }
        out[0] = (float)(1.0 - prod);
    }
}

extern "C" void kernel_launch(void* const* d_in, const int* in_sizes, int n_in,
                              void* d_out, int out_size, void* d_ws, size_t ws_size,
                              hipStream_t stream) {
    const float* img1 = (const float*)d_in[0];
    const float* img2 = (const float*)d_in[1];
    float* out = (float*)d_out;
    char* ws = (char*)d_ws;

    const int BC = in_sizes[0] / (512 * 512);   // 96

    double* accum = (double*)ws;
    size_t off = 8192;
    float* lvl1[5] = {nullptr, nullptr, nullptr, nullptr, nullptr};
    float* lvl2[5] = {nullptr, nullptr, nullptr, nullptr, nullptr};
    for (int l = 1; l < 5; ++l) {
        size_t hw = (size_t)(512 >> l) * (512 >> l);
        lvl1[l] = (float*)(ws + off); off += (size_t)BC * hw * sizeof(float);
        lvl2[l] = (float*)(ws + off); off += (size_t)BC * hw * sizeof(float);
    }

    hipMemsetAsync(accum, 0, 5 * 2 * 64 * sizeof(double), stream);

    // Gaussian window, faithful to the reference's POSITIVE exponent bug
    Coeffs cf;
    {
        double kd[11], sum = 0.0;
        for (int i = 0; i < 11; ++i) { kd[i] = exp(((double)((i-5)*(i-5))) / 4.5); sum += kd[i]; }
        for (int i = 0; i < 11; ++i) cf.k[i] = (float)(kd[i] / sum);
    }

    const float* cur1 = img1;
    const float* cur2 = img2;
    for (int lvl = 0; lvl < 5; ++lvl) {
        int H = 512 >> lvl, W = H;
        int tilesX = W / 32;
        int tilesY = H / 32;
        dim3 grid(tilesX * tilesY, BC);
        float* n1 = (lvl < 4) ? lvl1[lvl + 1] : nullptr;
        float* n2 = (lvl < 4) ? lvl2[lvl + 1] : nullptr;
        if (lvl < 2) {
            ssim_level_mfma<<<grid, 256, 0, stream>>>(cur1, cur2, n1, n2, H, W, tilesX,
                                                      accum + lvl * 128, cf);
        } else {
            ssim_level_f32<<<grid, 256, 0, stream>>>(cur1, cur2, n1, n2, H, W, tilesX,
                                                     accum + lvl * 128, cf);
        }
        cur1 = n1; cur2 = n2;
    }

    finalize_kernel<<<1, 64, 0, stream>>>(accum, out, BC);
}

// Round 6
// 240.364 us; speedup vs baseline: 1.1705x; 1.1705x over previous
//
#include <hip/hip_runtime.h>
#include <cmath>

typedef short bf16x8 __attribute__((ext_vector_type(8)));
typedef float f32x4 __attribute__((ext_vector_type(4)));

struct Coeffs { float k[11]; };

__device__ __forceinline__ ushort f2bf(float f) {          // RNE bf16 (finite inputs)
    unsigned u = __float_as_uint(f);
    u += 0x7fff + ((u >> 16) & 1);
    return (ushort)(u >> 16);
}

__device__ __forceinline__ unsigned pk2(float lo, float hi) {  // packed bf16 pair
    unsigned d;
    asm("v_cvt_pk_bf16_f32 %0, %1, %2" : "=v"(d) : "v"(lo), "v"(hi));
    return d;
}

// XOR-swizzled LDS address: 128-B rows, 8x16B slots, slot ^= row&7 (G4 recipe)
__device__ __forceinline__ void* sptr(void* base, int row, int colb) {
    return (void*)((char*)base + row * 128 + (colb ^ ((row & 7) << 4)));
}
__device__ __forceinline__ const void* sptrc(const void* base, int row, int colb) {
    return (const void*)((const char*)base + row * 128 + (colb ^ ((row & 7) << 4)));
}

__device__ __forceinline__ float4 ld4s(const float* __restrict__ p, int r, int c, int H, int W) {
    float4 v = make_float4(0.f, 0.f, 0.f, 0.f);
    if (r >= 0 && r < H) {
        const float* row = p + (size_t)r * W;
        if (c >= 0 && c + 3 < W) {
            v = *reinterpret_cast<const float4*>(row + c);
        } else {
            if (c + 0 >= 0 && c + 0 < W) v.x = row[c + 0];
            if (c + 1 >= 0 && c + 1 < W) v.y = row[c + 1];
            if (c + 2 >= 0 && c + 2 < W) v.z = row[c + 2];
            if (c + 3 >= 0 && c + 3 < W) v.w = row[c + 3];
        }
    }
    return v;
}

union FragU { ushort us[8]; bf16x8 v; uint4 q; };
union RdU   { uint4 q; bf16x8 v; };

// ============ init: build banded MFMA fragments once into d_ws =====================
__global__ __launch_bounds__(64)
void init_frag_kernel(uint4* __restrict__ tab, Coeffs cf) {
    const int lane = threadIdx.x;
    const int lj   = lane & 15;
    const int part = lane >> 4;
    FragU bHf, aVf;
    #pragma unroll
    for (int i = 0; i < 8; ++i) {
        const int kk = part * 8 + i;
        const int tH = kk - lj - 3;     // B_H[kk][j] = k[kk-j-3]
        const int tV = kk - lj;         // A_V[j][kk] = k[kk-j]
        float vH = 0.f, vV = 0.f;
        #pragma unroll
        for (int tt = 0; tt < 11; ++tt) {
            vH = (tH == tt) ? cf.k[tt] : vH;
            vV = (tV == tt) ? cf.k[tt] : vV;
        }
        bHf.us[i] = f2bf(vH);
        aVf.us[i] = f2bf(vV);
    }
    tab[lane]      = bHf.q;
    tab[64 + lane] = aVf.q;
}

// ============ MFMA kernel: levels 0-1 (large variance, bf16-safe) ==================
__global__ __launch_bounds__(256)
void ssim_level_mfma(const float* __restrict__ i1, const float* __restrict__ i2,
                     float* __restrict__ o1, float* __restrict__ o2,
                     int H, int W, int tilesX,
                     double* __restrict__ accum,
                     const uint4* __restrict__ frag_tab)
{
    __shared__ __align__(16) ushort A_lds[5][48][64];   // 30.7 KB, swizzled
    __shared__ __align__(16) ushort H_T [5][32][64];    // 20.5 KB, swizzled
    __shared__ double red[2][4];

    const int tid  = threadIdx.x;
    const int lane = tid & 63;
    const int wave = tid >> 6;
    const int lj   = lane & 15;
    const int part = lane >> 4;

    const int bc    = blockIdx.y;
    const int tileY = blockIdx.x / tilesX;
    const int tileX = blockIdx.x - tileY * tilesX;
    const int r0 = tileY * 32;
    const int c0 = tileX * 32;
    const float* p1 = i1 + (size_t)bc * H * W;
    const float* p2 = i2 + (size_t)bc * H * W;

    // constant banded fragments: 2 coalesced loads (L2-broadcast)
    RdU bHu, aVu;
    bHu.q = frag_tab[lane];
    aVu.q = frag_tab[64 + lane];
    const bf16x8 bH = bHu.v;
    const bf16x8 aV = aVu.v;

    // ---- Phase 1: load + products + bf16 pack -> A_lds (192 thr); pool (64 thr) ----
    if (tid < 192) {
        const int row_rel = tid >> 2;          // 0..47
        const int colg    = tid & 3;
        const int gr  = r0 - 5 + row_rel;
        const int gc0 = c0 - 8 + 12 * colg;

        float a[12], b[12];
        if (gr >= 0 && gr < H && gc0 >= 0 && gc0 + 12 <= W) {
            const float* pa = p1 + (size_t)gr * W + gc0;
            const float* pb = p2 + (size_t)gr * W + gc0;
            #pragma unroll
            for (int g = 0; g < 3; ++g) {
                float4 va = *reinterpret_cast<const float4*>(pa + 4 * g);
                float4 vb = *reinterpret_cast<const float4*>(pb + 4 * g);
                a[4*g+0]=va.x; a[4*g+1]=va.y; a[4*g+2]=va.z; a[4*g+3]=va.w;
                b[4*g+0]=vb.x; b[4*g+1]=vb.y; b[4*g+2]=vb.z; b[4*g+3]=vb.w;
            }
        } else {
            #pragma unroll
            for (int g = 0; g < 3; ++g) {
                float4 va = ld4s(p1, gr, gc0 + 4 * g, H, W);
                float4 vb = ld4s(p2, gr, gc0 + 4 * g, H, W);
                a[4*g+0]=va.x; a[4*g+1]=va.y; a[4*g+2]=va.z; a[4*g+3]=va.w;
                b[4*g+0]=vb.x; b[4*g+1]=vb.y; b[4*g+2]=vb.z; b[4*g+3]=vb.w;
            }
        }

        unsigned pks[5][6];
        #pragma unroll
        for (int e = 0; e < 6; ++e) {
            const float a0 = a[2*e], a1 = a[2*e+1];
            const float b0 = b[2*e], b1 = b[2*e+1];
            pks[0][e] = pk2(a0, a1);
            pks[1][e] = pk2(b0, b1);
            pks[2][e] = pk2(a0*a0, a1*a1);
            pks[3][e] = pk2(b0*b0, b1*b1);
            pks[4][e] = pk2(a0*b0, a1*b1);
        }
        const int cb = 24 * colg;
        #pragma unroll
        for (int s = 0; s < 5; ++s) {
            ushort* base = &A_lds[s][0][0];
            *(uint2*)sptr(base, row_rel, cb)      = make_uint2(pks[s][0], pks[s][1]);
            *(uint2*)sptr(base, row_rel, cb + 8)  = make_uint2(pks[s][2], pks[s][3]);
            *(uint2*)sptr(base, row_rel, cb + 16) = make_uint2(pks[s][4], pks[s][5]);
        }
    } else if (o1 != nullptr) {
        const int p = tid - 192;
        const int i = p & 15;
        const int h = p >> 4;
        const int gr0 = r0 + 2 * i;
        const int gc  = c0 + 8 * h;
        const float* pa = p1 + (size_t)gr0 * W + gc;
        const float* pb = p2 + (size_t)gr0 * W + gc;
        float4 a00 = *reinterpret_cast<const float4*>(pa);
        float4 a01 = *reinterpret_cast<const float4*>(pa + 4);
        float4 a10 = *reinterpret_cast<const float4*>(pa + W);
        float4 a11 = *reinterpret_cast<const float4*>(pa + W + 4);
        float4 b00 = *reinterpret_cast<const float4*>(pb);
        float4 b01 = *reinterpret_cast<const float4*>(pb + 4);
        float4 b10 = *reinterpret_cast<const float4*>(pb + W);
        float4 b11 = *reinterpret_cast<const float4*>(pb + W + 4);
        float4 oa, ob;
        oa.x = 0.25f*(a00.x+a00.y+a10.x+a10.y); oa.y = 0.25f*(a00.z+a00.w+a10.z+a10.w);
        oa.z = 0.25f*(a01.x+a01.y+a11.x+a11.y); oa.w = 0.25f*(a01.z+a01.w+a11.z+a11.w);
        ob.x = 0.25f*(b00.x+b00.y+b10.x+b10.y); ob.y = 0.25f*(b00.z+b00.w+b10.z+b10.w);
        ob.z = 0.25f*(b01.x+b01.y+b11.x+b11.y); ob.w = 0.25f*(b01.z+b01.w+b11.z+b11.w);
        const int W2 = W >> 1;
        const size_t base = (size_t)bc * (size_t)(H >> 1) * W2
                          + (size_t)(r0/2 + i) * W2 + (c0/2 + 4*h);
        *reinterpret_cast<float4*>(o1 + base) = oa;
        *reinterpret_cast<float4*>(o2 + base) = ob;
    }
    __syncthreads();

    // ---- Phase 2: H-conv via MFMA, write transposed bf16 (swizzled) ----
    const f32x4 zf = {0.f, 0.f, 0.f, 0.f};
    #pragma unroll
    for (int j = 0; j < 8; ++j) {
        const int id = wave + 4 * j;     // 30 MFMAs: rg(3) x cg(2) x s(5)
        if (id < 30) {
            const int rg  = id / 10;
            const int rem = id - rg * 10;
            const int cg  = rem / 5;
            const int s   = rem - cg * 5;
            RdU ar;
            ar.q = *(const uint4*)sptrc(&A_lds[s][0][0], rg*16 + lj, cg*32 + part*16);
            f32x4 d = __builtin_amdgcn_mfma_f32_16x16x32_bf16(ar.v, bH, zf, 0, 0, 0);
            *(uint2*)sptr(&H_T[s][0][0], 16*cg + lj, rg*32 + part*8)
                = make_uint2(pk2(d[0], d[1]), pk2(d[2], d[3]));
        }
    }
    __syncthreads();

    // ---- Phase 3: V-conv via MFMA + SSIM ----
    const int rg2 = wave >> 1;
    const int cg2 = wave & 1;
    f32x4 acc[5];
    #pragma unroll
    for (int s = 0; s < 5; ++s) {
        RdU br;
        br.q = *(const uint4*)sptrc(&H_T[s][0][0], 16*cg2 + lj, rg2*32 + part*16);
        acc[s] = __builtin_amdgcn_mfma_f32_16x16x32_bf16(aV, br.v, zf, 0, 0, 0);
    }

    const float C1 = 1e-4f, C2 = 9e-4f;
    float ssim_acc = 0.f, cs_acc = 0.f;
    #pragma unroll
    for (int r = 0; r < 4; ++r) {
        const float mu1 = acc[0][r], mu2 = acc[1][r];
        const float m11 = acc[2][r], m22 = acc[3][r], m12 = acc[4][r];
        const float mu1s = mu1 * mu1, mu2s = mu2 * mu2, mu12 = mu1 * mu2;
        const float v1 = 2.f * (m12 - mu12) + C2;
        const float v2 = (m11 - mu1s) + (m22 - mu2s) + C2;
        cs_acc   += v1 / v2;
        ssim_acc += ((2.f * mu12 + C1) * v1) / ((mu1s + mu2s + C1) * v2);
    }

    double sd = (double)ssim_acc, cd = (double)cs_acc;
    #pragma unroll
    for (int off = 32; off > 0; off >>= 1) {
        sd += __shfl_down(sd, off);
        cd += __shfl_down(cd, off);
    }
    if ((tid & 63) == 0) { red[0][wave] = sd; red[1][wave] = cd; }
    __syncthreads();
    if (tid == 0) {
        double s = red[0][0] + red[0][1] + red[0][2] + red[0][3];
        double c = red[1][0] + red[1][1] + red[1][2] + red[1][3];
        int slot = (blockIdx.x + blockIdx.y) & 63;
        atomicAdd(&accum[slot], s);
        atomicAdd(&accum[64 + slot], c);
    }
}

// =================== f32 kernel (R3, proven): levels 2-4 ===========================
#define TWF 32
#define THF 32
#define SPF 33
#define HRF 42

__global__ __launch_bounds__(256)
void ssim_level_f32(const float* __restrict__ i1, const float* __restrict__ i2,
                    float* __restrict__ o1, float* __restrict__ o2,
                    int H, int W, int tilesX,
                    double* __restrict__ accum, Coeffs cf)
{
    __shared__ __align__(16) float varr[5][HRF][SPF];
    __shared__ __align__(16) float phl[2][16][16];
    __shared__ double red[2][4];

    const int tid = threadIdx.x;
    const int bc  = blockIdx.y;
    const int tileY = blockIdx.x / tilesX;
    const int tileX = blockIdx.x - tileY * tilesX;
    const int r0 = tileY * THF;
    const int c0 = tileX * TWF;
    const float* p1 = i1 + (size_t)bc * H * W;
    const float* p2 = i2 + (size_t)bc * H * W;

    const int row_rel = tid >> 2;
    const int j  = tid & 3;
    const int cl = 8 * j;
    float hpA[4], hpB[4];
    bool pool_thread = false;

    if (tid < HRF * 4) {
        const int gr  = r0 + row_rel - 5;
        const int gcb = c0 + cl - 8;

        float a[24], b[24];
        if (gr >= 0 && gr < H && gcb >= 0 && gcb + 24 <= W) {
            const float* pa = p1 + (size_t)gr * W + gcb;
            const float* pb = p2 + (size_t)gr * W + gcb;
            #pragma unroll
            for (int g = 0; g < 6; ++g) {
                float4 va = *reinterpret_cast<const float4*>(pa + 4 * g);
                float4 vb = *reinterpret_cast<const float4*>(pb + 4 * g);
                a[4*g+0]=va.x; a[4*g+1]=va.y; a[4*g+2]=va.z; a[4*g+3]=va.w;
                b[4*g+0]=vb.x; b[4*g+1]=vb.y; b[4*g+2]=vb.z; b[4*g+3]=vb.w;
            }
        } else {
            #pragma unroll
            for (int g = 0; g < 6; ++g) {
                float4 va = ld4s(p1, gr, gcb + 4 * g, H, W);
                float4 vb = ld4s(p2, gr, gcb + 4 * g, H, W);
                a[4*g+0]=va.x; a[4*g+1]=va.y; a[4*g+2]=va.z; a[4*g+3]=va.w;
                b[4*g+0]=vb.x; b[4*g+1]=vb.y; b[4*g+2]=vb.z; b[4*g+3]=vb.w;
            }
        }

        float acc[5][8] = {};
        #pragma unroll
        for (int i = 0; i < 24; ++i) {
            float av = a[i], bv = b[i];
            float pa2 = av * av, pb2 = bv * bv, pab = av * bv;
            #pragma unroll
            for (int jo = 0; jo < 8; ++jo) {
                const int t = i - 3 - jo;
                if (t >= 0 && t <= 10) {
                    const float kk = cf.k[t];
                    acc[0][jo] += kk * av;  acc[1][jo] += kk * bv;
                    acc[2][jo] += kk * pa2; acc[3][jo] += kk * pb2;
                    acc[4][jo] += kk * pab;
                }
            }
        }
        #pragma unroll
        for (int s = 0; s < 5; ++s) {
            *reinterpret_cast<float4*>(&varr[s][row_rel][cl]) =
                make_float4(acc[s][0], acc[s][1], acc[s][2], acc[s][3]);
            *reinterpret_cast<float4*>(&varr[s][row_rel][cl + 4]) =
                make_float4(acc[s][4], acc[s][5], acc[s][6], acc[s][7]);
        }

        if (o1 != nullptr && row_rel >= 5 && row_rel <= 36) {
            #pragma unroll
            for (int p = 0; p < 4; ++p) {
                hpA[p] = a[8 + 2*p] + a[9 + 2*p];
                hpB[p] = b[8 + 2*p] + b[9 + 2*p];
            }
            if (row_rel & 1) {
                const int i = (row_rel - 5) >> 1;
                *reinterpret_cast<float4*>(&phl[0][i][4*j]) = make_float4(hpA[0],hpA[1],hpA[2],hpA[3]);
                *reinterpret_cast<float4*>(&phl[1][i][4*j]) = make_float4(hpB[0],hpB[1],hpB[2],hpB[3]);
            } else if (row_rel >= 6) {
                pool_thread = true;
            }
        }
    }
    __syncthreads();

    if (pool_thread) {
        const int i = (row_rel - 6) >> 1;
        const int W2 = W >> 1;
        float4 qa = *reinterpret_cast<const float4*>(&phl[0][i][4*j]);
        float4 qb = *reinterpret_cast<const float4*>(&phl[1][i][4*j]);
        qa.x = 0.25f*(qa.x + hpA[0]); qa.y = 0.25f*(qa.y + hpA[1]);
        qa.z = 0.25f*(qa.z + hpA[2]); qa.w = 0.25f*(qa.w + hpA[3]);
        qb.x = 0.25f*(qb.x + hpB[0]); qb.y = 0.25f*(qb.y + hpB[1]);
        qb.z = 0.25f*(qb.z + hpB[2]); qb.w = 0.25f*(qb.w + hpB[3]);
        const size_t base = (size_t)bc * (size_t)(H >> 1) * W2
                          + (size_t)(r0/2 + i) * W2 + (c0/2 + 4*j);
        *reinterpret_cast<float4*>(o1 + base) = qa;
        *reinterpret_cast<float4*>(o2 + base) = qb;
    }

    const int col = tid & 31;
    const int rg  = tid >> 5;

    float acc[5][4] = {};
    #pragma unroll
    for (int t = 0; t < 14; ++t) {
        const int m = rg * 4 + t;
        #pragma unroll
        for (int s = 0; s < 5; ++s) {
            const float val = varr[s][m][col];
            #pragma unroll
            for (int i = 0; i < 4; ++i) {
                const int tap = t - i;
                if (tap >= 0 && tap <= 10) acc[s][i] += cf.k[tap] * val;
            }
        }
    }

    const float C1 = 1e-4f, C2 = 9e-4f;
    float ssim_acc = 0.f, cs_acc = 0.f;
    #pragma unroll
    for (int i = 0; i < 4; ++i) {
        const float mu1 = acc[0][i], mu2 = acc[1][i];
        const float m11 = acc[2][i], m22 = acc[3][i], m12 = acc[4][i];
        const float mu1s = mu1 * mu1, mu2s = mu2 * mu2, mu12 = mu1 * mu2;
        const float v1 = 2.f * (m12 - mu12) + C2;
        const float v2 = (m11 - mu1s) + (m22 - mu2s) + C2;
        cs_acc   += v1 / v2;
        ssim_acc += ((2.f * mu12 + C1) * v1) / ((mu1s + mu2s + C1) * v2);
    }

    double sd = (double)ssim_acc, cd = (double)cs_acc;
    #pragma unroll
    for (int off = 32; off > 0; off >>= 1) {
        sd += __shfl_down(sd, off);
        cd += __shfl_down(cd, off);
    }
    const int wave = tid >> 6, lane = tid & 63;
    if (lane == 0) { red[0][wave] = sd; red[1][wave] = cd; }
    __syncthreads();
    if (tid == 0) {
        double s = red[0][0] + red[0][1] + red[0][2] + red[0][3];
        double c = red[1][0] + red[1][1] + red[1][2] + red[1][3];
        int slot = (blockIdx.x + blockIdx.y) & 63;
        atomicAdd(&accum[slot], s);
        atomicAdd(&accum[64 + slot], c);
    }
}

__global__ __launch_bounds__(64)
void finalize_kernel(const double* __restrict__ accum,  // [5][2][64]
                     float* __restrict__ out, int BC)
{
    __shared__ double sums[5][2];
    int tid = threadIdx.x;
    for (int lvl = 0; lvl < 5; ++lvl) {
        for (int m = 0; m < 2; ++m) {
            double v = accum[(lvl * 2 + m) * 64 + tid];
            for (int off = 32; off > 0; off >>= 1) v += __shfl_down(v, off);
            if (tid == 0) sums[lvl][m] = v;
        }
    }
    __syncthreads();
    if (tid == 0) {
        const double w[5] = {0.0448, 0.2856, 0.3001, 0.2363, 0.1333};
        double prod = 1.0;
        for (int lvl = 0; lvl < 5; ++lvl) {
            int hw = (512 >> lvl);
            double cnt = (double)BC * (double)hw * (double)hw;
            double mssim = sums[lvl][0] / cnt;
            double mcs   = sums[lvl][1] / cnt;
            if (lvl < 4) {
                prod *= pow(mcs, w[lvl]);
            } else {
                double p2 = pow(mssim, w[4]);
                prod *= p2 * p2 * p2 * p2;
            }
        }
        out[0] = (float)(1.0 - prod);
    }
}

extern "C" void kernel_launch(void* const* d_in, const int* in_sizes, int n_in,
                              void* d_out, int out_size, void* d_ws, size_t ws_size,
                              hipStream_t stream) {
    const float* img1 = (const float*)d_in[0];
    const float* img2 = (const float*)d_in[1];
    float* out = (float*)d_out;
    char* ws = (char*)d_ws;

    const int BC = in_sizes[0] / (512 * 512);   // 96

    // ws layout: [0,5120) accum; [6144,8192) frag table; pyramid from 8192
    double* accum = (double*)ws;
    uint4*  ftab  = (uint4*)(ws + 6144);
    size_t off = 8192;
    float* lvl1[5] = {nullptr, nullptr, nullptr, nullptr, nullptr};
    float* lvl2[5] = {nullptr, nullptr, nullptr, nullptr, nullptr};
    for (int l = 1; l < 5; ++l) {
        size_t hw = (size_t)(512 >> l) * (512 >> l);
        lvl1[l] = (float*)(ws + off); off += (size_t)BC * hw * sizeof(float);
        lvl2[l] = (float*)(ws + off); off += (size_t)BC * hw * sizeof(float);
    }

    hipMemsetAsync(accum, 0, 5 * 2 * 64 * sizeof(double), stream);

    // Gaussian window, faithful to the reference's POSITIVE exponent bug
    Coeffs cf;
    {
        double kd[11], sum = 0.0;
        for (int i = 0; i < 11; ++i) { kd[i] = exp(((double)((i-5)*(i-5))) / 4.5); sum += kd[i]; }
        for (int i = 0; i < 11; ++i) cf.k[i] = (float)(kd[i] / sum);
    }

    init_frag_kernel<<<1, 64, 0, stream>>>(ftab, cf);

    const float* cur1 = img1;
    const float* cur2 = img2;
    for (int lvl = 0; lvl < 5; ++lvl) {
        int H = 512 >> lvl, W = H;
        int tilesX = W / 32;
        int tilesY = H / 32;
        dim3 grid(tilesX * tilesY, BC);
        float* n1 = (lvl < 4) ? lvl1[lvl + 1] : nullptr;
        float* n2 = (lvl < 4) ? lvl2[lvl + 1] : nullptr;
        if (lvl < 2) {
            ssim_level_mfma<<<grid, 256, 0, stream>>>(cur1, cur2, n1, n2, H, W, tilesX,
                                                      accum + lvl * 128, ftab);
        } else {
            ssim_level_f32<<<grid, 256, 0, stream>>>(cur1, cur2, n1, n2, H, W, tilesX,
                                                     accum + lvl * 128, cf);
        }
        cur1 = n1; cur2 = n2;
    }

    finalize_kernel<<<1, 64, 0, stream>>>(accum, out, BC);
}

// Round 7
// 221.900 us; speedup vs baseline: 1.2679x; 1.0832x over previous
//
#include <hip/hip_runtime.h>
#include <cmath>

typedef short bf16x8 __attribute__((ext_vector_type(8)));
typedef float f32x4 __attribute__((ext_vector_type(4)));

struct Coeffs { float k[11]; };

__device__ __forceinline__ ushort f2bf(float f) {          // RNE bf16 (finite inputs)
    unsigned u = __float_as_uint(f);
    u += 0x7fff + ((u >> 16) & 1);
    return (ushort)(u >> 16);
}

__device__ __forceinline__ unsigned pk2(float lo, float hi) {  // packed bf16 pair
    unsigned d;
    asm("v_cvt_pk_bf16_f32 %0, %1, %2" : "=v"(d) : "v"(lo), "v"(hi));
    return d;
}

__device__ __forceinline__ float frcp(float x) { return __builtin_amdgcn_rcpf(x); }

__device__ __forceinline__ float4 ld4s(const float* __restrict__ p, int r, int c, int H, int W) {
    float4 v = make_float4(0.f, 0.f, 0.f, 0.f);
    if (r >= 0 && r < H) {
        const float* row = p + (size_t)r * W;
        if (c >= 0 && c + 3 < W) {
            v = *reinterpret_cast<const float4*>(row + c);
        } else {
            if (c + 0 >= 0 && c + 0 < W) v.x = row[c + 0];
            if (c + 1 >= 0 && c + 1 < W) v.y = row[c + 1];
            if (c + 2 >= 0 && c + 2 < W) v.z = row[c + 2];
            if (c + 3 >= 0 && c + 3 < W) v.w = row[c + 3];
        }
    }
    return v;
}

union FragU { ushort us[8]; bf16x8 v; uint4 q; };
union RdU   { uint4 q; bf16x8 v; };

// ============ init: build banded MFMA fragments once into d_ws =====================
__global__ __launch_bounds__(64)
void init_frag_kernel(uint4* __restrict__ tab, Coeffs cf) {
    const int lane = threadIdx.x;
    const int lj   = lane & 15;
    const int part = lane >> 4;
    FragU bHf, aVf;
    #pragma unroll
    for (int i = 0; i < 8; ++i) {
        const int kk = part * 8 + i;
        const int tH = kk - lj - 3;     // B_H[kk][j] = k[kk-j-3]
        const int tV = kk - lj;         // A_V[j][kk] = k[kk-j]
        float vH = 0.f, vV = 0.f;
        #pragma unroll
        for (int tt = 0; tt < 11; ++tt) {
            vH = (tH == tt) ? cf.k[tt] : vH;
            vV = (tV == tt) ? cf.k[tt] : vV;
        }
        bHf.us[i] = f2bf(vH);
        aVf.us[i] = f2bf(vV);
    }
    tab[lane]      = bHf.q;
    tab[64 + lane] = aVf.q;
}

// ============ MFMA kernel: levels 0-1 (large variance, bf16-safe) ==================
// grid: (tilesX, tilesY, B*C)
__global__ __launch_bounds__(256)
void ssim_level_mfma(const float* __restrict__ i1, const float* __restrict__ i2,
                     float* __restrict__ o1, float* __restrict__ o2,
                     int H, int W,
                     double* __restrict__ accum,
                     const uint4* __restrict__ frag_tab)
{
    // A_lds: [5 streams][48 region rows][64 ushort = 128B], XOR-swizzled cols
    // H_T :  [5 streams][32 out-cols][64 ushort],       XOR-swizzled cols
    __shared__ __align__(16) ushort A_lds[5][48][64];   // 30.7 KB
    __shared__ __align__(16) ushort H_T [5][32][64];    // 20.5 KB
    __shared__ double red[2][4];

    const int tid  = threadIdx.x;
    const int lane = tid & 63;
    const int lj   = lane & 15;
    const int part = lane >> 4;
    const int swz  = (lane & 7) << 4;
    const int wv   = __builtin_amdgcn_readfirstlane(tid) >> 6;   // wave id, SGPR

    const int bc = blockIdx.z;
    const int r0 = blockIdx.y * 32;
    const int c0 = blockIdx.x * 32;
    const float* p1 = i1 + (size_t)bc * H * W;
    const float* p2 = i2 + (size_t)bc * H * W;

    // constant banded fragments: 2 coalesced loads (L2-broadcast)
    RdU bHu, aVu;
    bHu.q = frag_tab[lane];
    aVu.q = frag_tab[64 + lane];
    const bf16x8 bH = bHu.v;
    const bf16x8 aV = aVu.v;

    // ---- Phase 1: load + products + bf16 pack -> A_lds (192 thr); pool (64 thr) ----
    if (tid < 192) {
        const int row_rel = tid >> 2;          // 0..47
        const int colg    = tid & 3;
        const int gr  = r0 - 5 + row_rel;
        const int gc0 = c0 - 8 + 12 * colg;

        float a[12], b[12];
        if (gr >= 0 && gr < H && gc0 >= 0 && gc0 + 12 <= W) {
            const size_t idx = (size_t)gr * W + gc0;
            const float* pa = p1 + idx;
            const float* pb = p2 + idx;
            #pragma unroll
            for (int g = 0; g < 3; ++g) {
                float4 va = *reinterpret_cast<const float4*>(pa + 4 * g);
                float4 vb = *reinterpret_cast<const float4*>(pb + 4 * g);
                a[4*g+0]=va.x; a[4*g+1]=va.y; a[4*g+2]=va.z; a[4*g+3]=va.w;
                b[4*g+0]=vb.x; b[4*g+1]=vb.y; b[4*g+2]=vb.z; b[4*g+3]=vb.w;
            }
        } else {
            #pragma unroll
            for (int g = 0; g < 3; ++g) {
                float4 va = ld4s(p1, gr, gc0 + 4 * g, H, W);
                float4 vb = ld4s(p2, gr, gc0 + 4 * g, H, W);
                a[4*g+0]=va.x; a[4*g+1]=va.y; a[4*g+2]=va.z; a[4*g+3]=va.w;
                b[4*g+0]=vb.x; b[4*g+1]=vb.y; b[4*g+2]=vb.z; b[4*g+3]=vb.w;
            }
        }

        unsigned pks[5][6];
        #pragma unroll
        for (int e = 0; e < 6; ++e) {
            const float a0 = a[2*e], a1 = a[2*e+1];
            const float b0 = b[2*e], b1 = b[2*e+1];
            pks[0][e] = pk2(a0, a1);
            pks[1][e] = pk2(b0, b1);
            pks[2][e] = pk2(a0*a0, a1*a1);
            pks[3][e] = pk2(b0*b0, b1*b1);
            pks[4][e] = pk2(a0*b0, a1*b1);
        }
        // 3 swizzled col addresses, stream stride folded as literal ds offset
        const int cb   = 24 * colg;
        const int swzr = (row_rel & 7) << 4;
        char* base0 = (char*)&A_lds[0][0][0] + row_rel * 128;
        char* q0 = base0 + ((cb)      ^ swzr);
        char* q1 = base0 + ((cb + 8)  ^ swzr);
        char* q2 = base0 + ((cb + 16) ^ swzr);
        #pragma unroll
        for (int s = 0; s < 5; ++s) {
            *(uint2*)(q0 + s * 6144) = make_uint2(pks[s][0], pks[s][1]);
            *(uint2*)(q1 + s * 6144) = make_uint2(pks[s][2], pks[s][3]);
            *(uint2*)(q2 + s * 6144) = make_uint2(pks[s][4], pks[s][5]);
        }
    } else if (o1 != nullptr) {
        // ---- fused 2x2 avg-pool (f32-exact), wave 3 ----
        const int p = tid - 192;
        const int i = p & 15;
        const int h = p >> 4;
        const size_t idx = (size_t)(r0 + 2 * i) * W + (c0 + 8 * h);
        const float* pa = p1 + idx;
        const float* pb = p2 + idx;
        float4 a00 = *reinterpret_cast<const float4*>(pa);
        float4 a01 = *reinterpret_cast<const float4*>(pa + 4);
        float4 a10 = *reinterpret_cast<const float4*>(pa + W);
        float4 a11 = *reinterpret_cast<const float4*>(pa + W + 4);
        float4 b00 = *reinterpret_cast<const float4*>(pb);
        float4 b01 = *reinterpret_cast<const float4*>(pb + 4);
        float4 b10 = *reinterpret_cast<const float4*>(pb + W);
        float4 b11 = *reinterpret_cast<const float4*>(pb + W + 4);
        float4 oa, ob;
        oa.x = 0.25f*(a00.x+a00.y+a10.x+a10.y); oa.y = 0.25f*(a00.z+a00.w+a10.z+a10.w);
        oa.z = 0.25f*(a01.x+a01.y+a11.x+a11.y); oa.w = 0.25f*(a01.z+a01.w+a11.z+a11.w);
        ob.x = 0.25f*(b00.x+b00.y+b10.x+b10.y); ob.y = 0.25f*(b00.z+b00.w+b10.z+b10.w);
        ob.z = 0.25f*(b01.x+b01.y+b11.x+b11.y); ob.w = 0.25f*(b01.z+b01.w+b11.z+b11.w);
        const int W2 = W >> 1;
        const size_t base = (size_t)bc * (size_t)(H >> 1) * W2
                          + (size_t)(r0/2 + i) * W2 + (c0/2 + 4*h);
        *reinterpret_cast<float4*>(o1 + base) = oa;
        *reinterpret_cast<float4*>(o2 + base) = ob;
    }
    __syncthreads();

    // ---- Phase 2: H-conv via MFMA (waves 0-2, rg = wv), write transposed bf16 ----
    const f32x4 zf = {0.f, 0.f, 0.f, 0.f};
    if (wv < 3) {
        const char* Ab = (const char*)&A_lds[0][0][0] + wv * 2048 + lj * 128;
        const char* a0 = Ab + ((part * 16)      ^ swz);
        const char* a1 = Ab + ((32 + part * 16) ^ swz);
        char* st = (char*)&H_T[0][0][0] + lj * 128 + ((wv * 32 + part * 8) ^ swz);
        #pragma unroll
        for (int s = 0; s < 5; ++s) {
            RdU r0u, r1u;
            r0u.q = *(const uint4*)(a0 + s * 6144);
            r1u.q = *(const uint4*)(a1 + s * 6144);
            f32x4 d0 = __builtin_amdgcn_mfma_f32_16x16x32_bf16(r0u.v, bH, zf, 0, 0, 0);
            f32x4 d1 = __builtin_amdgcn_mfma_f32_16x16x32_bf16(r1u.v, bH, zf, 0, 0, 0);
            *(uint2*)(st + s * 4096)        = make_uint2(pk2(d0[0], d0[1]), pk2(d0[2], d0[3]));
            *(uint2*)(st + s * 4096 + 2048) = make_uint2(pk2(d1[0], d1[1]), pk2(d1[2], d1[3]));
        }
    }
    __syncthreads();

    // ---- Phase 3: V-conv via MFMA + SSIM (all waves; rg2=wv>>1, cg2=wv&1) ----
    const int rg2 = wv >> 1;
    const int cg2 = wv & 1;
    const char* hb = (const char*)&H_T[0][0][0] + cg2 * 2048 + lj * 128
                   + ((rg2 * 32 + part * 16) ^ swz);
    f32x4 acc[5];
    #pragma unroll
    for (int s = 0; s < 5; ++s) {
        RdU br;
        br.q = *(const uint4*)(hb + s * 4096);
        acc[s] = __builtin_amdgcn_mfma_f32_16x16x32_bf16(aV, br.v, zf, 0, 0, 0);
    }

    const float C1 = 1e-4f, C2 = 9e-4f;
    float ssim_acc = 0.f, cs_acc = 0.f;
    #pragma unroll
    for (int r = 0; r < 4; ++r) {
        const float mu1 = acc[0][r], mu2 = acc[1][r];
        const float m11 = acc[2][r], m22 = acc[3][r], m12 = acc[4][r];
        const float mu1s = mu1 * mu1, mu2s = mu2 * mu2, mu12 = mu1 * mu2;
        const float v1 = 2.f * (m12 - mu12) + C2;
        const float v2 = (m11 - mu1s) + (m22 - mu2s) + C2;
        const float r2 = frcp(v2);
        const float rd = frcp(mu1s + mu2s + C1);
        cs_acc   += v1 * r2;
        ssim_acc += (2.f * mu12 + C1) * v1 * r2 * rd;
    }

    // ---- reduction: f32 within wave, double across waves ----
    #pragma unroll
    for (int off = 32; off > 0; off >>= 1) {
        ssim_acc += __shfl_down(ssim_acc, off);
        cs_acc   += __shfl_down(cs_acc, off);
    }
    if (lane == 0) { red[0][wv] = (double)ssim_acc; red[1][wv] = (double)cs_acc; }
    __syncthreads();
    if (tid == 0) {
        double s = red[0][0] + red[0][1] + red[0][2] + red[0][3];
        double c = red[1][0] + red[1][1] + red[1][2] + red[1][3];
        int slot = (blockIdx.x + blockIdx.y * 3 + blockIdx.z * 7) & 63;
        atomicAdd(&accum[slot], s);
        atomicAdd(&accum[64 + slot], c);
    }
}

// =================== f32 kernel (R3, proven): levels 2-4 ===========================
#define SPF 33
#define HRF 42

__global__ __launch_bounds__(256)
void ssim_level_f32(const float* __restrict__ i1, const float* __restrict__ i2,
                    float* __restrict__ o1, float* __restrict__ o2,
                    int H, int W,
                    double* __restrict__ accum, Coeffs cf)
{
    __shared__ __align__(16) float varr[5][HRF][SPF];
    __shared__ __align__(16) float phl[2][16][16];
    __shared__ double red[2][4];

    const int tid = threadIdx.x;
    const int bc  = blockIdx.z;
    const int r0 = blockIdx.y * 32;
    const int c0 = blockIdx.x * 32;
    const float* p1 = i1 + (size_t)bc * H * W;
    const float* p2 = i2 + (size_t)bc * H * W;

    const int row_rel = tid >> 2;
    const int j  = tid & 3;
    const int cl = 8 * j;
    float hpA[4], hpB[4];
    bool pool_thread = false;

    if (tid < HRF * 4) {
        const int gr  = r0 + row_rel - 5;
        const int gcb = c0 + cl - 8;

        float a[24], b[24];
        if (gr >= 0 && gr < H && gcb >= 0 && gcb + 24 <= W) {
            const size_t idx = (size_t)gr * W + gcb;
            const float* pa = p1 + idx;
            const float* pb = p2 + idx;
            #pragma unroll
            for (int g = 0; g < 6; ++g) {
                float4 va = *reinterpret_cast<const float4*>(pa + 4 * g);
                float4 vb = *reinterpret_cast<const float4*>(pb + 4 * g);
                a[4*g+0]=va.x; a[4*g+1]=va.y; a[4*g+2]=va.z; a[4*g+3]=va.w;
                b[4*g+0]=vb.x; b[4*g+1]=vb.y; b[4*g+2]=vb.z; b[4*g+3]=vb.w;
            }
        } else {
            #pragma unroll
            for (int g = 0; g < 6; ++g) {
                float4 va = ld4s(p1, gr, gcb + 4 * g, H, W);
                float4 vb = ld4s(p2, gr, gcb + 4 * g, H, W);
                a[4*g+0]=va.x; a[4*g+1]=va.y; a[4*g+2]=va.z; a[4*g+3]=va.w;
                b[4*g+0]=vb.x; b[4*g+1]=vb.y; b[4*g+2]=vb.z; b[4*g+3]=vb.w;
            }
        }

        float acc[5][8] = {};
        #pragma unroll
        for (int i = 0; i < 24; ++i) {
            float av = a[i], bv = b[i];
            float pa2 = av * av, pb2 = bv * bv, pab = av * bv;
            #pragma unroll
            for (int jo = 0; jo < 8; ++jo) {
                const int t = i - 3 - jo;
                if (t >= 0 && t <= 10) {
                    const float kk = cf.k[t];
                    acc[0][jo] += kk * av;  acc[1][jo] += kk * bv;
                    acc[2][jo] += kk * pa2; acc[3][jo] += kk * pb2;
                    acc[4][jo] += kk * pab;
                }
            }
        }
        #pragma unroll
        for (int s = 0; s < 5; ++s) {
            *reinterpret_cast<float4*>(&varr[s][row_rel][cl]) =
                make_float4(acc[s][0], acc[s][1], acc[s][2], acc[s][3]);
            *reinterpret_cast<float4*>(&varr[s][row_rel][cl + 4]) =
                make_float4(acc[s][4], acc[s][5], acc[s][6], acc[s][7]);
        }

        if (o1 != nullptr && row_rel >= 5 && row_rel <= 36) {
            #pragma unroll
            for (int p = 0; p < 4; ++p) {
                hpA[p] = a[8 + 2*p] + a[9 + 2*p];
                hpB[p] = b[8 + 2*p] + b[9 + 2*p];
            }
            if (row_rel & 1) {
                const int i = (row_rel - 5) >> 1;
                *reinterpret_cast<float4*>(&phl[0][i][4*j]) = make_float4(hpA[0],hpA[1],hpA[2],hpA[3]);
                *reinterpret_cast<float4*>(&phl[1][i][4*j]) = make_float4(hpB[0],hpB[1],hpB[2],hpB[3]);
            } else if (row_rel >= 6) {
                pool_thread = true;
            }
        }
    }
    __syncthreads();

    if (pool_thread) {
        const int i = (row_rel - 6) >> 1;
        const int W2 = W >> 1;
        float4 qa = *reinterpret_cast<const float4*>(&phl[0][i][4*j]);
        float4 qb = *reinterpret_cast<const float4*>(&phl[1][i][4*j]);
        qa.x = 0.25f*(qa.x + hpA[0]); qa.y = 0.25f*(qa.y + hpA[1]);
        qa.z = 0.25f*(qa.z + hpA[2]); qa.w = 0.25f*(qa.w + hpA[3]);
        qb.x = 0.25f*(qb.x + hpB[0]); qb.y = 0.25f*(qb.y + hpB[1]);
        qb.z = 0.25f*(qb.z + hpB[2]); qb.w = 0.25f*(qb.w + hpB[3]);
        const size_t base = (size_t)bc * (size_t)(H >> 1) * W2
                          + (size_t)(r0/2 + i) * W2 + (c0/2 + 4*j);
        *reinterpret_cast<float4*>(o1 + base) = qa;
        *reinterpret_cast<float4*>(o2 + base) = qb;
    }

    const int col = tid & 31;
    const int rg  = tid >> 5;

    float acc[5][4] = {};
    #pragma unroll
    for (int t = 0; t < 14; ++t) {
        const int m = rg * 4 + t;
        #pragma unroll
        for (int s = 0; s < 5; ++s) {
            const float val = varr[s][m][col];
            #pragma unroll
            for (int i = 0; i < 4; ++i) {
                const int tap = t - i;
                if (tap >= 0 && tap <= 10) acc[s][i] += cf.k[tap] * val;
            }
        }
    }

    const float C1 = 1e-4f, C2 = 9e-4f;
    float ssim_acc = 0.f, cs_acc = 0.f;
    #pragma unroll
    for (int i = 0; i < 4; ++i) {
        const float mu1 = acc[0][i], mu2 = acc[1][i];
        const float m11 = acc[2][i], m22 = acc[3][i], m12 = acc[4][i];
        const float mu1s = mu1 * mu1, mu2s = mu2 * mu2, mu12 = mu1 * mu2;
        const float v1 = 2.f * (m12 - mu12) + C2;
        const float v2 = (m11 - mu1s) + (m22 - mu2s) + C2;
        const float r2 = frcp(v2);
        const float rd = frcp(mu1s + mu2s + C1);
        cs_acc   += v1 * r2;
        ssim_acc += (2.f * mu12 + C1) * v1 * r2 * rd;
    }

    #pragma unroll
    for (int off = 32; off > 0; off >>= 1) {
        ssim_acc += __shfl_down(ssim_acc, off);
        cs_acc   += __shfl_down(cs_acc, off);
    }
    const int wave = tid >> 6, lane = tid & 63;
    if (lane == 0) { red[0][wave] = (double)ssim_acc; red[1][wave] = (double)cs_acc; }
    __syncthreads();
    if (tid == 0) {
        double s = red[0][0] + red[0][1] + red[0][2] + red[0][3];
        double c = red[1][0] + red[1][1] + red[1][2] + red[1][3];
        int slot = (blockIdx.x + blockIdx.y * 3 + blockIdx.z * 7) & 63;
        atomicAdd(&accum[slot], s);
        atomicAdd(&accum[64 + slot], c);
    }
}

__global__ __launch_bounds__(64)
void finalize_kernel(const double* __restrict__ accum,  // [5][2][64]
                     float* __restrict__ out, int BC)
{
    __shared__ double sums[5][2];
    int tid = threadIdx.x;
    for (int lvl = 0; lvl < 5; ++lvl) {
        for (int m = 0; m < 2; ++m) {
            double v = accum[(lvl * 2 + m) * 64 + tid];
            for (int off = 32; off > 0; off >>= 1) v += __shfl_down(v, off);
            if (tid == 0) sums[lvl][m] = v;
        }
    }
    __syncthreads();
    if (tid == 0) {
        const double w[5] = {0.0448, 0.2856, 0.3001, 0.2363, 0.1333};
        double prod = 1.0;
        for (int lvl = 0; lvl < 5; ++lvl) {
            int hw = (512 >> lvl);
            double cnt = (double)BC * (double)hw * (double)hw;
            double mssim = sums[lvl][0] / cnt;
            double mcs   = sums[lvl][1] / cnt;
            if (lvl < 4) {
                prod *= pow(mcs, w[lvl]);
            } else {
                double p2 = pow(mssim, w[4]);
                prod *= p2 * p2 * p2 * p2;
            }
        }
        out[0] = (float)(1.0 - prod);
    }
}

extern "C" void kernel_launch(void* const* d_in, const int* in_sizes, int n_in,
                              void* d_out, int out_size, void* d_ws, size_t ws_size,
                              hipStream_t stream) {
    const float* img1 = (const float*)d_in[0];
    const float* img2 = (const float*)d_in[1];
    float* out = (float*)d_out;
    char* ws = (char*)d_ws;

    const int BC = in_sizes[0] / (512 * 512);   // 96

    // ws layout: [0,5120) accum; [6144,8192) frag table; pyramid from 8192
    double* accum = (double*)ws;
    uint4*  ftab  = (uint4*)(ws + 6144);
    size_t off = 8192;
    float* lvl1[5] = {nullptr, nullptr, nullptr, nullptr, nullptr};
    float* lvl2[5] = {nullptr, nullptr, nullptr, nullptr, nullptr};
    for (int l = 1; l < 5; ++l) {
        size_t hw = (size_t)(512 >> l) * (512 >> l);
        lvl1[l] = (float*)(ws + off); off += (size_t)BC * hw * sizeof(float);
        lvl2[l] = (float*)(ws + off); off += (size_t)BC * hw * sizeof(float);
    }

    hipMemsetAsync(accum, 0, 5 * 2 * 64 * sizeof(double), stream);

    // Gaussian window, faithful to the reference's POSITIVE exponent bug
    Coeffs cf;
    {
        double kd[11], sum = 0.0;
        for (int i = 0; i < 11; ++i) { kd[i] = exp(((double)((i-5)*(i-5))) / 4.5); sum += kd[i]; }
        for (int i = 0; i < 11; ++i) cf.k[i] = (float)(kd[i] / sum);
    }

    init_frag_kernel<<<1, 64, 0, stream>>>(ftab, cf);

    const float* cur1 = img1;
    const float* cur2 = img2;
    for (int lvl = 0; lvl < 5; ++lvl) {
        int H = 512 >> lvl, W = H;
        dim3 grid(W / 32, H / 32, BC);
        float* n1 = (lvl < 4) ? lvl1[lvl + 1] : nullptr;
        float* n2 = (lvl < 4) ? lvl2[lvl + 1] : nullptr;
        if (lvl < 2) {
            ssim_level_mfma<<<grid, 256, 0, stream>>>(cur1, cur2, n1, n2, H, W,
                                                      accum + lvl * 128, ftab);
        } else {
            ssim_level_f32<<<grid, 256, 0, stream>>>(cur1, cur2, n1, n2, H, W,
                                                     accum + lvl * 128, cf);
        }
        cur1 = n1; cur2 = n2;
    }

    finalize_kernel<<<1, 64, 0, stream>>>(accum, out, BC);
}

// Round 8
// 195.031 us; speedup vs baseline: 1.4426x; 1.1378x over previous
//
#include <hip/hip_runtime.h>
#include <cmath>

typedef short bf16x8 __attribute__((ext_vector_type(8)));
typedef float f32x4 __attribute__((ext_vector_type(4)));

struct Coeffs { float k[11]; };

__device__ __forceinline__ ushort f2bf(float f) {          // RNE bf16 (finite inputs)
    unsigned u = __float_as_uint(f);
    u += 0x7fff + ((u >> 16) & 1);
    return (ushort)(u >> 16);
}

__device__ __forceinline__ unsigned pk2(float lo, float hi) {  // packed bf16 pair
    unsigned d;
    asm("v_cvt_pk_bf16_f32 %0, %1, %2" : "=v"(d) : "v"(lo), "v"(hi));
    return d;
}

__device__ __forceinline__ float frcp(float x) { return __builtin_amdgcn_rcpf(x); }

__device__ __forceinline__ float4 ld4s(const float* __restrict__ p, int r, int c, int H, int W) {
    float4 v = make_float4(0.f, 0.f, 0.f, 0.f);
    if (r >= 0 && r < H) {
        const float* row = p + (size_t)r * W;
        if (c >= 0 && c + 3 < W) {
            v = *reinterpret_cast<const float4*>(row + c);
        } else {
            if (c + 0 >= 0 && c + 0 < W) v.x = row[c + 0];
            if (c + 1 >= 0 && c + 1 < W) v.y = row[c + 1];
            if (c + 2 >= 0 && c + 2 < W) v.z = row[c + 2];
            if (c + 3 >= 0 && c + 3 < W) v.w = row[c + 3];
        }
    }
    return v;
}

union FragU { ushort us[8]; bf16x8 v; uint4 q; };
union RdU   { uint4 q; bf16x8 v; };

// ============ init: build banded MFMA fragments once into d_ws =====================
__global__ __launch_bounds__(64)
void init_frag_kernel(uint4* __restrict__ tab, Coeffs cf) {
    const int lane = threadIdx.x;
    const int lj   = lane & 15;
    const int part = lane >> 4;
    FragU bHf, aVf;
    #pragma unroll
    for (int i = 0; i < 8; ++i) {
        const int kk = part * 8 + i;
        const int tH = kk - lj - 3;     // B_H[kk][j] = k[kk-j-3]
        const int tV = kk - lj;         // A_V[j][kk] = k[kk-j]
        float vH = 0.f, vV = 0.f;
        #pragma unroll
        for (int tt = 0; tt < 11; ++tt) {
            vH = (tH == tt) ? cf.k[tt] : vH;
            vV = (tV == tt) ? cf.k[tt] : vV;
        }
        bHf.us[i] = f2bf(vH);
        aVf.us[i] = f2bf(vV);
    }
    tab[lane]      = bHf.q;
    tab[64 + lane] = aVf.q;
}

// ============ MFMA kernel: levels 0-1 (large variance, bf16-safe) ==================
// grid: (tilesX, tilesY, B*C). Waves 0-2: direct global->reg A-fragments, H-MFMA.
// Wave 3: f32-exact 2x2 avg-pool. One barrier, then V-MFMA + SSIM on all waves.
__global__ __launch_bounds__(256)
void ssim_level_mfma(const float* __restrict__ i1, const float* __restrict__ i2,
                     float* __restrict__ o1, float* __restrict__ o2,
                     int H, int W,
                     double* __restrict__ accum,
                     const uint4* __restrict__ frag_tab)
{
    // H_T: [5 streams][32 out-cols][64 ushort = 128B], XOR-swizzled cols. 20.5 KB.
    __shared__ __align__(16) ushort H_T[5][32][64];
    __shared__ double red[2][4];

    const int tid  = threadIdx.x;
    const int lane = tid & 63;
    const int lj   = lane & 15;
    const int part = lane >> 4;
    const int swz  = (lane & 7) << 4;
    const int wv   = __builtin_amdgcn_readfirstlane(tid) >> 6;   // wave id, SGPR

    const int bc = blockIdx.z;
    const int r0 = blockIdx.y * 32;
    const int c0 = blockIdx.x * 32;
    const float* p1 = i1 + (size_t)bc * H * W;
    const float* p2 = i2 + (size_t)bc * H * W;

    // constant banded fragments: 2 coalesced loads (L2-broadcast)
    RdU bHu, aVu;
    bHu.q = frag_tab[lane];
    aVu.q = frag_tab[64 + lane];
    const bf16x8 bH = bHu.v;
    const bf16x8 aV = aVu.v;

    const f32x4 zf = {0.f, 0.f, 0.f, 0.f};

    if (wv < 3) {
        // ---- H-conv: A-fragment straight from global (row rg*16+lj, k=part*8+i) ----
        const int gr = r0 - 5 + wv * 16 + lj;
        char* st = (char*)&H_T[0][0][0] + lj * 128 + ((wv * 32 + part * 8) ^ swz);
        #pragma unroll
        for (int cg = 0; cg < 2; ++cg) {
            const int gc = c0 - 8 + cg * 16 + part * 8;
            float a8[8], b8[8];
            if (gr >= 0 && gr < H && gc >= 0 && gc + 8 <= W) {
                const size_t idx = (size_t)gr * W + gc;
                float4 va0 = *reinterpret_cast<const float4*>(p1 + idx);
                float4 va1 = *reinterpret_cast<const float4*>(p1 + idx + 4);
                float4 vb0 = *reinterpret_cast<const float4*>(p2 + idx);
                float4 vb1 = *reinterpret_cast<const float4*>(p2 + idx + 4);
                a8[0]=va0.x; a8[1]=va0.y; a8[2]=va0.z; a8[3]=va0.w;
                a8[4]=va1.x; a8[5]=va1.y; a8[6]=va1.z; a8[7]=va1.w;
                b8[0]=vb0.x; b8[1]=vb0.y; b8[2]=vb0.z; b8[3]=vb0.w;
                b8[4]=vb1.x; b8[5]=vb1.y; b8[6]=vb1.z; b8[7]=vb1.w;
            } else {
                float4 va0 = ld4s(p1, gr, gc, H, W);
                float4 va1 = ld4s(p1, gr, gc + 4, H, W);
                float4 vb0 = ld4s(p2, gr, gc, H, W);
                float4 vb1 = ld4s(p2, gr, gc + 4, H, W);
                a8[0]=va0.x; a8[1]=va0.y; a8[2]=va0.z; a8[3]=va0.w;
                a8[4]=va1.x; a8[5]=va1.y; a8[6]=va1.z; a8[7]=va1.w;
                b8[0]=vb0.x; b8[1]=vb0.y; b8[2]=vb0.z; b8[3]=vb0.w;
                b8[4]=vb1.x; b8[5]=vb1.y; b8[6]=vb1.z; b8[7]=vb1.w;
            }

            unsigned pkf[5][4];
            #pragma unroll
            for (int e = 0; e < 4; ++e) {
                const float a0 = a8[2*e], a1 = a8[2*e+1];
                const float b0 = b8[2*e], b1 = b8[2*e+1];
                pkf[0][e] = pk2(a0, a1);
                pkf[1][e] = pk2(b0, b1);
                pkf[2][e] = pk2(a0*a0, a1*a1);
                pkf[3][e] = pk2(b0*b0, b1*b1);
                pkf[4][e] = pk2(a0*b0, a1*b1);
            }
            #pragma unroll
            for (int s = 0; s < 5; ++s) {
                RdU fr;
                fr.q.x = pkf[s][0]; fr.q.y = pkf[s][1];
                fr.q.z = pkf[s][2]; fr.q.w = pkf[s][3];
                f32x4 d = __builtin_amdgcn_mfma_f32_16x16x32_bf16(fr.v, bH, zf, 0, 0, 0);
                *(uint2*)(st + cg * 2048 + s * 4096)
                    = make_uint2(pk2(d[0], d[1]), pk2(d[2], d[3]));
            }
        }
    } else if (o1 != nullptr) {
        // ---- fused 2x2 avg-pool (f32-exact), wave 3 ----
        const int p = tid - 192;
        const int i = p & 15;
        const int h = p >> 4;
        const size_t idx = (size_t)(r0 + 2 * i) * W + (c0 + 8 * h);
        const float* pa = p1 + idx;
        const float* pb = p2 + idx;
        float4 a00 = *reinterpret_cast<const float4*>(pa);
        float4 a01 = *reinterpret_cast<const float4*>(pa + 4);
        float4 a10 = *reinterpret_cast<const float4*>(pa + W);
        float4 a11 = *reinterpret_cast<const float4*>(pa + W + 4);
        float4 b00 = *reinterpret_cast<const float4*>(pb);
        float4 b01 = *reinterpret_cast<const float4*>(pb + 4);
        float4 b10 = *reinterpret_cast<const float4*>(pb + W);
        float4 b11 = *reinterpret_cast<const float4*>(pb + W + 4);
        float4 oa, ob;
        oa.x = 0.25f*(a00.x+a00.y+a10.x+a10.y); oa.y = 0.25f*(a00.z+a00.w+a10.z+a10.w);
        oa.z = 0.25f*(a01.x+a01.y+a11.x+a11.y); oa.w = 0.25f*(a01.z+a01.w+a11.z+a11.w);
        ob.x = 0.25f*(b00.x+b00.y+b10.x+b10.y); ob.y = 0.25f*(b00.z+b00.w+b10.z+b10.w);
        ob.z = 0.25f*(b01.x+b01.y+b11.x+b11.y); ob.w = 0.25f*(b01.z+b01.w+b11.z+b11.w);
        const int W2 = W >> 1;
        const size_t base = (size_t)bc * (size_t)(H >> 1) * W2
                          + (size_t)(r0/2 + i) * W2 + (c0/2 + 4*h);
        *reinterpret_cast<float4*>(o1 + base) = oa;
        *reinterpret_cast<float4*>(o2 + base) = ob;
    }
    __syncthreads();

    // ---- V-conv via MFMA + SSIM (all waves; rg2=wv>>1, cg2=wv&1) ----
    const int rg2 = wv >> 1;
    const int cg2 = wv & 1;
    const char* hb = (const char*)&H_T[0][0][0] + cg2 * 2048 + lj * 128
                   + ((rg2 * 32 + part * 16) ^ swz);
    f32x4 acc[5];
    #pragma unroll
    for (int s = 0; s < 5; ++s) {
        RdU br;
        br.q = *(const uint4*)(hb + s * 4096);
        acc[s] = __builtin_amdgcn_mfma_f32_16x16x32_bf16(aV, br.v, zf, 0, 0, 0);
    }

    const float C1 = 1e-4f, C2 = 9e-4f;
    float ssim_acc = 0.f, cs_acc = 0.f;
    #pragma unroll
    for (int r = 0; r < 4; ++r) {
        const float mu1 = acc[0][r], mu2 = acc[1][r];
        const float m11 = acc[2][r], m22 = acc[3][r], m12 = acc[4][r];
        const float mu1s = mu1 * mu1, mu2s = mu2 * mu2, mu12 = mu1 * mu2;
        const float v1 = 2.f * (m12 - mu12) + C2;
        const float v2 = (m11 - mu1s) + (m22 - mu2s) + C2;
        const float r2 = frcp(v2);
        const float rd = frcp(mu1s + mu2s + C1);
        cs_acc   += v1 * r2;
        ssim_acc += (2.f * mu12 + C1) * v1 * r2 * rd;
    }

    // ---- reduction: f32 within wave, double across waves ----
    #pragma unroll
    for (int off = 32; off > 0; off >>= 1) {
        ssim_acc += __shfl_down(ssim_acc, off);
        cs_acc   += __shfl_down(cs_acc, off);
    }
    if (lane == 0) { red[0][wv] = (double)ssim_acc; red[1][wv] = (double)cs_acc; }
    __syncthreads();
    if (tid == 0) {
        double s = red[0][0] + red[0][1] + red[0][2] + red[0][3];
        double c = red[1][0] + red[1][1] + red[1][2] + red[1][3];
        int slot = (blockIdx.x + blockIdx.y * 3 + blockIdx.z * 7) & 63;
        atomicAdd(&accum[slot], s);
        atomicAdd(&accum[64 + slot], c);
    }
}

// =================== f32 kernel (R3, proven): levels 2-4 ===========================
#define SPF 33
#define HRF 42

__global__ __launch_bounds__(256)
void ssim_level_f32(const float* __restrict__ i1, const float* __restrict__ i2,
                    float* __restrict__ o1, float* __restrict__ o2,
                    int H, int W,
                    double* __restrict__ accum, Coeffs cf)
{
    __shared__ __align__(16) float varr[5][HRF][SPF];
    __shared__ __align__(16) float phl[2][16][16];
    __shared__ double red[2][4];

    const int tid = threadIdx.x;
    const int bc  = blockIdx.z;
    const int r0 = blockIdx.y * 32;
    const int c0 = blockIdx.x * 32;
    const float* p1 = i1 + (size_t)bc * H * W;
    const float* p2 = i2 + (size_t)bc * H * W;

    const int row_rel = tid >> 2;
    const int j  = tid & 3;
    const int cl = 8 * j;
    float hpA[4], hpB[4];
    bool pool_thread = false;

    if (tid < HRF * 4) {
        const int gr  = r0 + row_rel - 5;
        const int gcb = c0 + cl - 8;

        float a[24], b[24];
        if (gr >= 0 && gr < H && gcb >= 0 && gcb + 24 <= W) {
            const size_t idx = (size_t)gr * W + gcb;
            const float* pa = p1 + idx;
            const float* pb = p2 + idx;
            #pragma unroll
            for (int g = 0; g < 6; ++g) {
                float4 va = *reinterpret_cast<const float4*>(pa + 4 * g);
                float4 vb = *reinterpret_cast<const float4*>(pb + 4 * g);
                a[4*g+0]=va.x; a[4*g+1]=va.y; a[4*g+2]=va.z; a[4*g+3]=va.w;
                b[4*g+0]=vb.x; b[4*g+1]=vb.y; b[4*g+2]=vb.z; b[4*g+3]=vb.w;
            }
        } else {
            #pragma unroll
            for (int g = 0; g < 6; ++g) {
                float4 va = ld4s(p1, gr, gcb + 4 * g, H, W);
                float4 vb = ld4s(p2, gr, gcb + 4 * g, H, W);
                a[4*g+0]=va.x; a[4*g+1]=va.y; a[4*g+2]=va.z; a[4*g+3]=va.w;
                b[4*g+0]=vb.x; b[4*g+1]=vb.y; b[4*g+2]=vb.z; b[4*g+3]=vb.w;
            }
        }

        float acc[5][8] = {};
        #pragma unroll
        for (int i = 0; i < 24; ++i) {
            float av = a[i], bv = b[i];
            float pa2 = av * av, pb2 = bv * bv, pab = av * bv;
            #pragma unroll
            for (int jo = 0; jo < 8; ++jo) {
                const int t = i - 3 - jo;
                if (t >= 0 && t <= 10) {
                    const float kk = cf.k[t];
                    acc[0][jo] += kk * av;  acc[1][jo] += kk * bv;
                    acc[2][jo] += kk * pa2; acc[3][jo] += kk * pb2;
                    acc[4][jo] += kk * pab;
                }
            }
        }
        #pragma unroll
        for (int s = 0; s < 5; ++s) {
            *reinterpret_cast<float4*>(&varr[s][row_rel][cl]) =
                make_float4(acc[s][0], acc[s][1], acc[s][2], acc[s][3]);
            *reinterpret_cast<float4*>(&varr[s][row_rel][cl + 4]) =
                make_float4(acc[s][4], acc[s][5], acc[s][6], acc[s][7]);
        }

        if (o1 != nullptr && row_rel >= 5 && row_rel <= 36) {
            #pragma unroll
            for (int p = 0; p < 4; ++p) {
                hpA[p] = a[8 + 2*p] + a[9 + 2*p];
                hpB[p] = b[8 + 2*p] + b[9 + 2*p];
            }
            if (row_rel & 1) {
                const int i = (row_rel - 5) >> 1;
                *reinterpret_cast<float4*>(&phl[0][i][4*j]) = make_float4(hpA[0],hpA[1],hpA[2],hpA[3]);
                *reinterpret_cast<float4*>(&phl[1][i][4*j]) = make_float4(hpB[0],hpB[1],hpB[2],hpB[3]);
            } else if (row_rel >= 6) {
                pool_thread = true;
            }
        }
    }
    __syncthreads();

    if (pool_thread) {
        const int i = (row_rel - 6) >> 1;
        const int W2 = W >> 1;
        float4 qa = *reinterpret_cast<const float4*>(&phl[0][i][4*j]);
        float4 qb = *reinterpret_cast<const float4*>(&phl[1][i][4*j]);
        qa.x = 0.25f*(qa.x + hpA[0]); qa.y = 0.25f*(qa.y + hpA[1]);
        qa.z = 0.25f*(qa.z + hpA[2]); qa.w = 0.25f*(qa.w + hpA[3]);
        qb.x = 0.25f*(qb.x + hpB[0]); qb.y = 0.25f*(qb.y + hpB[1]);
        qb.z = 0.25f*(qb.z + hpB[2]); qb.w = 0.25f*(qb.w + hpB[3]);
        const size_t base = (size_t)bc * (size_t)(H >> 1) * W2
                          + (size_t)(r0/2 + i) * W2 + (c0/2 + 4*j);
        *reinterpret_cast<float4*>(o1 + base) = qa;
        *reinterpret_cast<float4*>(o2 + base) = qb;
    }

    const int col = tid & 31;
    const int rg  = tid >> 5;

    float acc[5][4] = {};
    #pragma unroll
    for (int t = 0; t < 14; ++t) {
        const int m = rg * 4 + t;
        #pragma unroll
        for (int s = 0; s < 5; ++s) {
            const float val = varr[s][m][col];
            #pragma unroll
            for (int i = 0; i < 4; ++i) {
                const int tap = t - i;
                if (tap >= 0 && tap <= 10) acc[s][i] += cf.k[tap] * val;
            }
        }
    }

    const float C1 = 1e-4f, C2 = 9e-4f;
    float ssim_acc = 0.f, cs_acc = 0.f;
    #pragma unroll
    for (int i = 0; i < 4; ++i) {
        const float mu1 = acc[0][i], mu2 = acc[1][i];
        const float m11 = acc[2][i], m22 = acc[3][i], m12 = acc[4][i];
        const float mu1s = mu1 * mu1, mu2s = mu2 * mu2, mu12 = mu1 * mu2;
        const float v1 = 2.f * (m12 - mu12) + C2;
        const float v2 = (m11 - mu1s) + (m22 - mu2s) + C2;
        const float r2 = frcp(v2);
        const float rd = frcp(mu1s + mu2s + C1);
        cs_acc   += v1 * r2;
        ssim_acc += (2.f * mu12 + C1) * v1 * r2 * rd;
    }

    #pragma unroll
    for (int off = 32; off > 0; off >>= 1) {
        ssim_acc += __shfl_down(ssim_acc, off);
        cs_acc   += __shfl_down(cs_acc, off);
    }
    const int wave = tid >> 6, lane = tid & 63;
    if (lane == 0) { red[0][wave] = (double)ssim_acc; red[1][wave] = (double)cs_acc; }
    __syncthreads();
    if (tid == 0) {
        double s = red[0][0] + red[0][1] + red[0][2] + red[0][3];
        double c = red[1][0] + red[1][1] + red[1][2] + red[1][3];
        int slot = (blockIdx.x + blockIdx.y * 3 + blockIdx.z * 7) & 63;
        atomicAdd(&accum[slot], s);
        atomicAdd(&accum[64 + slot], c);
    }
}

__global__ __launch_bounds__(64)
void finalize_kernel(const double* __restrict__ accum,  // [5][2][64]
                     float* __restrict__ out, int BC)
{
    __shared__ double sums[5][2];
    int tid = threadIdx.x;
    for (int lvl = 0; lvl < 5; ++lvl) {
        for (int m = 0; m < 2; ++m) {
            double v = accum[(lvl * 2 + m) * 64 + tid];
            for (int off = 32; off > 0; off >>= 1) v += __shfl_down(v, off);
            if (tid == 0) sums[lvl][m] = v;
        }
    }
    __syncthreads();
    if (tid == 0) {
        const double w[5] = {0.0448, 0.2856, 0.3001, 0.2363, 0.1333};
        double prod = 1.0;
        for (int lvl = 0; lvl < 5; ++lvl) {
            int hw = (512 >> lvl);
            double cnt = (double)BC * (double)hw * (double)hw;
            double mssim = sums[lvl][0] / cnt;
            double mcs   = sums[lvl][1] / cnt;
            if (lvl < 4) {
                prod *= pow(mcs, w[lvl]);
            } else {
                double p2 = pow(mssim, w[4]);
                prod *= p2 * p2 * p2 * p2;
            }
        }
        out[0] = (float)(1.0 - prod);
    }
}

extern "C" void kernel_launch(void* const* d_in, const int* in_sizes, int n_in,
                              void* d_out, int out_size, void* d_ws, size_t ws_size,
                              hipStream_t stream) {
    const float* img1 = (const float*)d_in[0];
    const float* img2 = (const float*)d_in[1];
    float* out = (float*)d_out;
    char* ws = (char*)d_ws;

    const int BC = in_sizes[0] / (512 * 512);   // 96

    // ws layout: [0,5120) accum; [6144,8192) frag table; pyramid from 8192
    double* accum = (double*)ws;
    uint4*  ftab  = (uint4*)(ws + 6144);
    size_t off = 8192;
    float* lvl1[5] = {nullptr, nullptr, nullptr, nullptr, nullptr};
    float* lvl2[5] = {nullptr, nullptr, nullptr, nullptr, nullptr};
    for (int l = 1; l < 5; ++l) {
        size_t hw = (size_t)(512 >> l) * (512 >> l);
        lvl1[l] = (float*)(ws + off); off += (size_t)BC * hw * sizeof(float);
        lvl2[l] = (float*)(ws + off); off += (size_t)BC * hw * sizeof(float);
    }

    hipMemsetAsync(accum, 0, 5 * 2 * 64 * sizeof(double), stream);

    // Gaussian window, faithful to the reference's POSITIVE exponent bug
    Coeffs cf;
    {
        double kd[11], sum = 0.0;
        for (int i = 0; i < 11; ++i) { kd[i] = exp(((double)((i-5)*(i-5))) / 4.5); sum += kd[i]; }
        for (int i = 0; i < 11; ++i) cf.k[i] = (float)(kd[i] / sum);
    }

    init_frag_kernel<<<1, 64, 0, stream>>>(ftab, cf);

    const float* cur1 = img1;
    const float* cur2 = img2;
    for (int lvl = 0; lvl < 5; ++lvl) {
        int H = 512 >> lvl, W = H;
        dim3 grid(W / 32, H / 32, BC);
        float* n1 = (lvl < 4) ? lvl1[lvl + 1] : nullptr;
        float* n2 = (lvl < 4) ? lvl2[lvl + 1] : nullptr;
        if (lvl < 2) {
            ssim_level_mfma<<<grid, 256, 0, stream>>>(cur1, cur2, n1, n2, H, W,
                                                      accum + lvl * 128, ftab);
        } else {
            ssim_level_f32<<<grid, 256, 0, stream>>>(cur1, cur2, n1, n2, H, W,
                                                     accum + lvl * 128, cf);
        }
        cur1 = n1; cur2 = n2;
    }

    finalize_kernel<<<1, 64, 0, stream>>>(accum, out, BC);
}